// Round 12
// baseline (540.061 us; speedup 1.0000x reference)
//
#include <hip/hip_runtime.h>

// VQ-VAE vector quantizer — DIAGNOSTIC ROUND (rep x3 main, x8 fin; idempotent).
// X: NCHW f32 (32,64,64,64); W: (512,64) f32.
// out: [0]=loss, [1..8388609)=quantized NCHW, [8388609]=perplexity,
//      [8388610..)=one-hot encodings [131072][512].
#define BHW 262144
#define OUT_Q_OFF 1
#define OUT_P_OFF 8388609
#define OUT_E_OFF 8388610

// ws layout (4-byte words):
// [0..256)      loss partial slots (f32)   -- memset 0
// [768..1280)   wsq = ||e_k||^2 (f32)
// [1280..17664) bf16 codebook B-fragments, PRE-SCALED by -2: [tn=32][j=2][lane=64] x 8
// [17664..148736) per-row argmin indices (i32)
#define IDX_W 17664

typedef __attribute__((ext_vector_type(8))) short short8;
typedef __attribute__((ext_vector_type(4))) float f32x4;
typedef __attribute__((ext_vector_type(2))) float f32x2;

__device__ __forceinline__ unsigned short f2bf(float f) {
    union { float f; unsigned u; } c; c.f = f;
    unsigned r = (c.u + 0x7FFFu + ((c.u >> 16) & 1u)) >> 16;  // RNE
    return (unsigned short)r;
}

__global__ __launch_bounds__(512) void vq_init(const float* __restrict__ W, float* __restrict__ ws) {
    const int tid = blockIdx.x * 512 + threadIdx.x;
    if (tid < 512) {
        const float4* W4 = (const float4*)W;
        float s = 0.f;
#pragma unroll
        for (int i = 0; i < 16; ++i) {
            float4 v = W4[tid * 16 + i];
            s = fmaf(v.x, v.x, s); s = fmaf(v.y, v.y, s);
            s = fmaf(v.z, v.z, s); s = fmaf(v.w, v.w, s);
        }
        ws[768 + tid] = s;
    } else {
        const int c  = tid - 512;            // 0..4095
        const int l  = c & 63;
        const int j  = (c >> 6) & 1;
        const int tn = c >> 7;
        const int n  = tn * 16 + (l & 15);
        const int k0 = j * 32 + ((l >> 4) & 3) * 8;
        const float* src = W + n * 64 + k0;
        unsigned h0 = f2bf(-2.f * src[0]) | ((unsigned)f2bf(-2.f * src[1]) << 16);
        unsigned h1 = f2bf(-2.f * src[2]) | ((unsigned)f2bf(-2.f * src[3]) << 16);
        unsigned h2 = f2bf(-2.f * src[4]) | ((unsigned)f2bf(-2.f * src[5]) << 16);
        unsigned h3 = f2bf(-2.f * src[6]) | ((unsigned)f2bf(-2.f * src[7]) << 16);
        uint4* dst = (uint4*)(ws + 1280);
        dst[c] = make_uint4(h0, h1, h2, h3);
    }
}

// vq_main: R10 structure, body repeated 3x (idempotent) so the dispatch exceeds
// the harness fill kernels and surfaces in rocprof top-5 WITH counters.
__global__ __launch_bounds__(256) void vq_main(const float* __restrict__ X,
                                               const float* __restrict__ W,
                                               float* __restrict__ out,
                                               float* __restrict__ ws) {
    const int t    = threadIdx.x;
    const int l    = t & 63;
    const int wv   = t >> 6;
    const int nlow = l & 15;
    const int kg   = l >> 4;
    const int rowbase = blockIdx.x * 64;
    const int b = rowbase >> 12;
    const int h = (rowbase >> 6) & 63;
    const int myrow = wv * 16 + nlow;

    __shared__ short8 Btab[2048];            // 32 KB half-table

    for (int rep = 0; rep < 3; ++rep) {
        asm volatile("" ::: "memory");       // force real reloads each rep (no CSE)

        // ---- this lane's x row (strided NCHW gather) ----
        const float* xr = X + (size_t)b * BHW + (size_t)h * 64 + myrow;
        float xf[16];
#pragma unroll
        for (int e = 0; e < 8; ++e) xf[e]     = xr[(size_t)(kg * 8 + e) * 4096];
#pragma unroll
        for (int e = 0; e < 8; ++e) xf[8 + e] = xr[(size_t)(32 + kg * 8 + e) * 4096];
        short8 a0, a1;
#pragma unroll
        for (int e = 0; e < 8; ++e) { a0[e] = (short)f2bf(xf[e]); a1[e] = (short)f2bf(xf[8 + e]); }

        // ---- scan all 512 codes from LDS-staged table ----
        const uint4* __restrict__ gtab = (const uint4*)(ws + 1280);
        const float* __restrict__ wsq  = ws + 768;
        float bS[4]; int bK[4];
#pragma unroll
        for (int r = 0; r < 4; ++r) { bS[r] = 3.4e38f; bK[r] = 0; }

        for (int half = 0; half < 2; ++half) {
            __syncthreads();
            uint4* bt = (uint4*)Btab;
#pragma unroll
            for (int i = 0; i < 8; ++i)
                bt[i * 256 + t] = gtab[half * 2048 + i * 256 + t];
            __syncthreads();
#pragma unroll 4
            for (int tn = 0; tn < 16; ++tn) {
                short8 f0 = Btab[tn * 128 + l];
                short8 f1 = Btab[tn * 128 + 64 + l];
                const int   n  = (half * 16 + tn) * 16 + nlow;
                const float wq = wsq[n];
                f32x4 acc = {wq, wq, wq, wq};
                acc = __builtin_amdgcn_mfma_f32_16x16x32_bf16(a0, f0, acc, 0, 0, 0);
                acc = __builtin_amdgcn_mfma_f32_16x16x32_bf16(a1, f1, acc, 0, 0, 0);
#pragma unroll
                for (int r = 0; r < 4; ++r) {
                    if (acc[r] < bS[r]) { bS[r] = acc[r]; bK[r] = n; }
                }
            }
        }
#pragma unroll
        for (int r = 0; r < 4; ++r) {
#pragma unroll
            for (int mask = 1; mask <= 8; mask <<= 1) {
                float os = __shfl_xor(bS[r], mask);
                int   ok = __shfl_xor(bK[r], mask);
                if (os < bS[r] || (os == bS[r] && ok < bK[r])) { bS[r] = os; bK[r] = ok; }
            }
        }

        // ---- per-row best broadcast; inline one-hot writes; idx store ----
        int rowBk = 0, myBk = 0;
        f32x2* encB = (f32x2*)(out + OUT_E_OFF);
        const size_t Rbase = (size_t)(rowbase + wv * 16);
#pragma unroll
        for (int m = 0; m < 16; ++m) {
            int bkm = __shfl(bK[m & 3], (m >> 2) * 16);
            if (nlow == m) rowBk = bkm;
            if (l == m)    myBk = bkm;
            f32x2* erow = encB + (Rbase + m) * 256;
#pragma unroll
            for (int c = 0; c < 4; ++c) {
                int p = c * 64 + l;
                f32x2 v;
                v.x = (bkm == 2 * p)     ? 1.f : 0.f;
                v.y = (bkm == 2 * p + 1) ? 1.f : 0.f;
                erow[p] = v;
            }
        }
        if (l < 16) ((int*)ws)[IDX_W + rowbase + wv * 16 + l] = myBk;

        // ---- quantized_st + loss partials ----
        const float4* W4 = (const float4*)W;
        float4 q0 = W4[rowBk * 16 + kg * 2];
        float4 q1 = W4[rowBk * 16 + kg * 2 + 1];
        float4 q2 = W4[rowBk * 16 + 8 + kg * 2];
        float4 q3 = W4[rowBk * 16 + 8 + kg * 2 + 1];
        float qv[16] = {q0.x, q0.y, q0.z, q0.w, q1.x, q1.y, q1.z, q1.w,
                        q2.x, q2.y, q2.z, q2.w, q3.x, q3.y, q3.z, q3.w};
        float lsum = 0.f;
        float* op = out + OUT_Q_OFF + (size_t)b * BHW + (size_t)h * 64 + myrow;
#pragma unroll
        for (int e = 0; e < 8; ++e) {
            float d0 = qv[e] - xf[e];
            lsum = fmaf(d0, d0, lsum);
            op[(size_t)(kg * 8 + e) * 4096] = xf[e] + d0;
            float d1 = qv[8 + e] - xf[8 + e];
            lsum = fmaf(d1, d1, lsum);
            op[(size_t)(32 + kg * 8 + e) * 4096] = xf[8 + e] + d1;
        }

#pragma unroll
        for (int off = 32; off >= 1; off >>= 1) lsum += __shfl_down(lsum, off);
        if (rep == 2 && l == 0) atomicAdd(ws + ((blockIdx.x * 4 + wv) & 255), lsum);
    }
}

// vq_fin: rep x8 (idempotent) — surfaces in top-5 iff its real cost >= ~22us.
__global__ __launch_bounds__(512) void vq_fin(const float* __restrict__ ws, float* __restrict__ out) {
    __shared__ unsigned hist[512];
    __shared__ float redP[8], redL[8];
    const int t = threadIdx.x;
    for (int rep = 0; rep < 8; ++rep) {
        asm volatile("" ::: "memory");
        hist[t] = 0u;
        __syncthreads();
        const uint4* __restrict__ idx4 = (const uint4*)((const int*)ws + IDX_W);
#pragma unroll 4
        for (int i = 0; i < 64; ++i) {
            uint4 v = idx4[i * 512 + t];
            atomicAdd(&hist[v.x], 1u);
            atomicAdd(&hist[v.y], 1u);
            atomicAdd(&hist[v.z], 1u);
            atomicAdd(&hist[v.w], 1u);
        }
        __syncthreads();
        float p = (float)hist[t] * (1.0f / 131072.0f);
        float s = p * logf(p + 1e-10f);
        float lp = (t < 256) ? ws[t] : 0.f;
#pragma unroll
        for (int off = 32; off >= 1; off >>= 1) {
            s  += __shfl_down(s, off);
            lp += __shfl_down(lp, off);
        }
        if ((t & 63) == 0) { redP[t >> 6] = s; redL[t >> 6] = lp; }
        __syncthreads();
        if (t == 0) {
            float tp = 0.f, tl = 0.f;
#pragma unroll
            for (int i = 0; i < 8; ++i) { tp += redP[i]; tl += redL[i]; }
            out[OUT_P_OFF] = expf(-tp);
            out[0] = tl * (1.25f / 8388608.0f);
        }
        __syncthreads();
    }
}

extern "C" void kernel_launch(void* const* d_in, const int* in_sizes, int n_in,
                              void* d_out, int out_size, void* d_ws, size_t ws_size,
                              hipStream_t stream) {
    const float* X = (const float*)d_in[0];
    const float* W = (const float*)d_in[1];
    float* out = (float*)d_out;
    float* ws  = (float*)d_ws;

    (void)hipMemsetAsync(d_ws, 0, 256 * sizeof(float), stream);   // loss slots
    vq_init<<<9, 512, 0, stream>>>(W, ws);
    vq_main<<<2048, 256, 0, stream>>>(X, W, out, ws);
    vq_fin<<<1, 512, 0, stream>>>(ws, out);
}

// Round 13
// 118.593 us; speedup vs baseline: 4.5539x; 4.5539x over previous
//
#include <hip/hip_runtime.h>

// VQ-VAE vector quantizer. N=131072 rows (32*64*64), D=64, K=512.
// X: NCHW f32 (32,64,64,64); W: (512,64) f32.
// out: [0]=loss, [1..8388609)=quantized NCHW, [8388609]=perplexity,
//      [8388610..)=one-hot encodings [131072][512].
#define BHW 262144
#define OUT_Q_OFF 1
#define OUT_P_OFF 8388609
#define OUT_E_OFF 8388610

// ws layout (4-byte words):
// [0..256)      loss partial slots (f32)   -- memset 0
// [768..1280)   wsq = ||e_k||^2 (f32)
// [1280..17664) bf16 codebook B-fragments, PRE-SCALED by -2: [tn=32][j=2][lane=64] x 8
// [17664..148736) per-row argmin indices (i32)
#define IDX_W 17664

typedef __attribute__((ext_vector_type(8))) short short8;
typedef __attribute__((ext_vector_type(4))) float f32x4;
typedef __attribute__((ext_vector_type(2))) float f32x2;

__device__ __forceinline__ unsigned short f2bf(float f) {
    union { float f; unsigned u; } c; c.f = f;
    unsigned r = (c.u + 0x7FFFu + ((c.u >> 16) & 1u)) >> 16;  // RNE
    return (unsigned short)r;
}

__global__ __launch_bounds__(512) void vq_init(const float* __restrict__ W, float* __restrict__ ws) {
    const int tid = blockIdx.x * 512 + threadIdx.x;
    if (tid < 512) {
        const float4* W4 = (const float4*)W;
        float s = 0.f;
#pragma unroll
        for (int i = 0; i < 16; ++i) {
            float4 v = W4[tid * 16 + i];
            s = fmaf(v.x, v.x, s); s = fmaf(v.y, v.y, s);
            s = fmaf(v.z, v.z, s); s = fmaf(v.w, v.w, s);
        }
        ws[768 + tid] = s;
    } else {
        const int c  = tid - 512;            // 0..4095
        const int l  = c & 63;
        const int j  = (c >> 6) & 1;
        const int tn = c >> 7;
        const int n  = tn * 16 + (l & 15);
        const int k0 = j * 32 + ((l >> 4) & 3) * 8;
        const float* src = W + n * 64 + k0;
        unsigned h0 = f2bf(-2.f * src[0]) | ((unsigned)f2bf(-2.f * src[1]) << 16);
        unsigned h1 = f2bf(-2.f * src[2]) | ((unsigned)f2bf(-2.f * src[3]) << 16);
        unsigned h2 = f2bf(-2.f * src[4]) | ((unsigned)f2bf(-2.f * src[5]) << 16);
        unsigned h3 = f2bf(-2.f * src[6]) | ((unsigned)f2bf(-2.f * src[7]) << 16);
        uint4* dst = (uint4*)(ws + 1280);
        dst[c] = make_uint4(h0, h1, h2, h3);
    }
}

// vq_main: 4 independent waves per block (no LDS, no barriers). Each wave owns
// TWO 16-row tiles (32 consecutive w's, same (b,h)) -> dual independent MFMA/
// compare chains per B8 load, 2x intensity, 2x ILP. All X loads issued up
// front; W gathers issued before the enc loop to hide latency under it.
__global__ __launch_bounds__(256) void vq_main(const float* __restrict__ X,
                                               const float* __restrict__ W,
                                               float* __restrict__ out,
                                               float* __restrict__ ws) {
    const int t    = threadIdx.x;
    const int l    = t & 63;
    const int wv   = t >> 6;
    const int nlow = l & 15;
    const int kg   = l >> 4;
    const int rowbase = (blockIdx.x * 4 + wv) * 32;  // 32 rows, same (b,h)
    const int b  = rowbase >> 12;
    const int h  = (rowbase >> 6) & 63;
    const int w0 = rowbase & 63;                     // 0 or 32

    // ---- both tiles' x rows (A-frag row = nlow), all 32 loads in flight ----
    const float* xr0 = X + (size_t)b * BHW + (size_t)h * 64 + (w0 + nlow);
    const float* xr1 = xr0 + 16;
    float xf0[16], xf1[16];
#pragma unroll
    for (int e = 0; e < 8; ++e) {
        xf0[e]     = xr0[(size_t)(kg * 8 + e) * 4096];
        xf0[8 + e] = xr0[(size_t)(32 + kg * 8 + e) * 4096];
        xf1[e]     = xr1[(size_t)(kg * 8 + e) * 4096];
        xf1[8 + e] = xr1[(size_t)(32 + kg * 8 + e) * 4096];
    }
    short8 a00, a01, a10, a11;
#pragma unroll
    for (int e = 0; e < 8; ++e) {
        a00[e] = (short)f2bf(xf0[e]); a01[e] = (short)f2bf(xf0[8 + e]);
        a10[e] = (short)f2bf(xf1[e]); a11[e] = (short)f2bf(xf1[8 + e]);
    }

    // ---- scan all 512 codes: dual tiles per B8 load ----
    const short8* __restrict__ B8  = (const short8*)(ws + 1280);
    const float*  __restrict__ wsq = ws + 768;
    float bS0[4], bS1[4]; int bK0[4], bK1[4];
#pragma unroll
    for (int r = 0; r < 4; ++r) { bS0[r] = 3.4e38f; bK0[r] = 0; bS1[r] = 3.4e38f; bK1[r] = 0; }

#pragma unroll 4
    for (int tn = 0; tn < 32; ++tn) {
        short8 f0 = B8[tn * 128 + l];
        short8 f1 = B8[tn * 128 + 64 + l];
        const float wq = wsq[tn * 16 + nlow];
        const int   n  = tn * 16 + nlow;
        f32x4 acc0 = {wq, wq, wq, wq};
        f32x4 acc1 = {wq, wq, wq, wq};
        acc0 = __builtin_amdgcn_mfma_f32_16x16x32_bf16(a00, f0, acc0, 0, 0, 0);
        acc1 = __builtin_amdgcn_mfma_f32_16x16x32_bf16(a10, f0, acc1, 0, 0, 0);
        acc0 = __builtin_amdgcn_mfma_f32_16x16x32_bf16(a01, f1, acc0, 0, 0, 0);
        acc1 = __builtin_amdgcn_mfma_f32_16x16x32_bf16(a11, f1, acc1, 0, 0, 0);
#pragma unroll
        for (int r = 0; r < 4; ++r) {
            if (acc0[r] < bS0[r]) { bS0[r] = acc0[r]; bK0[r] = n; }
            if (acc1[r] < bS1[r]) { bS1[r] = acc1[r]; bK1[r] = n; }
        }
    }
    // butterfly min-reduce over 16 code-lanes per kg group (lowest-k tiebreak);
    // 8 independent 4-step chains
#pragma unroll
    for (int r = 0; r < 4; ++r) {
#pragma unroll
        for (int mask = 1; mask <= 8; mask <<= 1) {
            float os; int ok;
            os = __shfl_xor(bS0[r], mask); ok = __shfl_xor(bK0[r], mask);
            if (os < bS0[r] || (os == bS0[r] && ok < bK0[r])) { bS0[r] = os; bK0[r] = ok; }
            os = __shfl_xor(bS1[r], mask); ok = __shfl_xor(bK1[r], mask);
            if (os < bS1[r] || (os == bS1[r] && ok < bK1[r])) { bS1[r] = os; bK1[r] = ok; }
        }
    }

    // ---- per-lane own-row best: 4 bpermutes + cndmask select (rows m=kg*4+r
    //      live in group kg; row nlow is held by group nlow>>2, reg nlow&3) ----
    const int src = (nlow >> 2) * 16;   // source lane within wave
    int g0, g1, g2, g3, sel = nlow & 3;
    g0 = __shfl(bK0[0], src); g1 = __shfl(bK0[1], src);
    g2 = __shfl(bK0[2], src); g3 = __shfl(bK0[3], src);
    const int rowBk0 = sel == 0 ? g0 : sel == 1 ? g1 : sel == 2 ? g2 : g3;
    g0 = __shfl(bK1[0], src); g1 = __shfl(bK1[1], src);
    g2 = __shfl(bK1[2], src); g3 = __shfl(bK1[3], src);
    const int rowBk1 = sel == 0 ? g0 : sel == 1 ? g1 : sel == 2 ? g2 : g3;

    // idx stores for fin histogram (lanes 0..31 cover the 32 rows)
    if (l < 32) ((int*)ws)[IDX_W + rowbase + l] = (l < 16) ? rowBk0 : rowBk1;

    // ---- issue W gathers NOW (latency hides under the enc loop) ----
    const float4* W4 = (const float4*)W;
    float4 p0 = W4[rowBk0 * 16 + kg * 2];
    float4 p1 = W4[rowBk0 * 16 + kg * 2 + 1];
    float4 p2 = W4[rowBk0 * 16 + 8 + kg * 2];
    float4 p3 = W4[rowBk0 * 16 + 8 + kg * 2 + 1];
    float4 s0 = W4[rowBk1 * 16 + kg * 2];
    float4 s1 = W4[rowBk1 * 16 + kg * 2 + 1];
    float4 s2 = W4[rowBk1 * 16 + 8 + kg * 2];
    float4 s3 = W4[rowBk1 * 16 + 8 + kg * 2 + 1];

    // ---- one-hot encodings for both tiles (coalesced f32x2 stores) ----
    f32x2* encB = (f32x2*)(out + OUT_E_OFF);
    const size_t R0 = (size_t)rowbase;
    const size_t R1 = (size_t)rowbase + 16;
#pragma unroll
    for (int m = 0; m < 16; ++m) {
        const int bkm0 = __shfl(bK0[m & 3], (m >> 2) * 16);
        const int bkm1 = __shfl(bK1[m & 3], (m >> 2) * 16);
        f32x2* e0 = encB + (R0 + m) * 256;
        f32x2* e1 = encB + (R1 + m) * 256;
#pragma unroll
        for (int c = 0; c < 4; ++c) {
            const int p = c * 64 + l;
            f32x2 v0, v1;
            v0.x = (bkm0 == 2 * p)     ? 1.f : 0.f;
            v0.y = (bkm0 == 2 * p + 1) ? 1.f : 0.f;
            v1.x = (bkm1 == 2 * p)     ? 1.f : 0.f;
            v1.y = (bkm1 == 2 * p + 1) ? 1.f : 0.f;
            e0[p] = v0;
            e1[p] = v1;
        }
    }

    // ---- quantized_st + loss for both tiles (x register-resident) ----
    float qa[16] = {p0.x, p0.y, p0.z, p0.w, p1.x, p1.y, p1.z, p1.w,
                    p2.x, p2.y, p2.z, p2.w, p3.x, p3.y, p3.z, p3.w};
    float qb[16] = {s0.x, s0.y, s0.z, s0.w, s1.x, s1.y, s1.z, s1.w,
                    s2.x, s2.y, s2.z, s2.w, s3.x, s3.y, s3.z, s3.w};
    float lsum = 0.f;
    float* op0 = out + OUT_Q_OFF + (size_t)b * BHW + (size_t)h * 64 + (w0 + nlow);
    float* op1 = op0 + 16;
#pragma unroll
    for (int e = 0; e < 8; ++e) {
        float d;
        d = qa[e] - xf0[e];          lsum = fmaf(d, d, lsum);
        op0[(size_t)(kg * 8 + e) * 4096] = xf0[e] + d;
        d = qa[8 + e] - xf0[8 + e];  lsum = fmaf(d, d, lsum);
        op0[(size_t)(32 + kg * 8 + e) * 4096] = xf0[8 + e] + d;
        d = qb[e] - xf1[e];          lsum = fmaf(d, d, lsum);
        op1[(size_t)(kg * 8 + e) * 4096] = xf1[e] + d;
        d = qb[8 + e] - xf1[8 + e];  lsum = fmaf(d, d, lsum);
        op1[(size_t)(32 + kg * 8 + e) * 4096] = xf1[8 + e] + d;
    }

    // ---- loss wave-reduce; spread atomics over 256 slots ----
#pragma unroll
    for (int off = 32; off >= 1; off >>= 1) lsum += __shfl_down(lsum, off);
    if (l == 0) atomicAdd(ws + ((blockIdx.x * 4 + wv) & 255), lsum);
}

// vq_fin: single block. LDS histogram of 131072 indices, then finalize.
__global__ __launch_bounds__(512) void vq_fin(const float* __restrict__ ws, float* __restrict__ out) {
    __shared__ unsigned hist[512];
    __shared__ float redP[8], redL[8];
    const int t = threadIdx.x;
    hist[t] = 0u;
    __syncthreads();
    const uint4* __restrict__ idx4 = (const uint4*)((const int*)ws + IDX_W);
#pragma unroll 4
    for (int i = 0; i < 64; ++i) {
        uint4 v = idx4[i * 512 + t];
        atomicAdd(&hist[v.x], 1u);
        atomicAdd(&hist[v.y], 1u);
        atomicAdd(&hist[v.z], 1u);
        atomicAdd(&hist[v.w], 1u);
    }
    __syncthreads();
    float p = (float)hist[t] * (1.0f / 131072.0f);
    float s = p * logf(p + 1e-10f);
    float lp = (t < 256) ? ws[t] : 0.f;
#pragma unroll
    for (int off = 32; off >= 1; off >>= 1) {
        s  += __shfl_down(s, off);
        lp += __shfl_down(lp, off);
    }
    if ((t & 63) == 0) { redP[t >> 6] = s; redL[t >> 6] = lp; }
    __syncthreads();
    if (t == 0) {
        float tp = 0.f, tl = 0.f;
#pragma unroll
        for (int i = 0; i < 8; ++i) { tp += redP[i]; tl += redL[i]; }
        out[OUT_P_OFF] = expf(-tp);
        out[0] = tl * (1.25f / 8388608.0f);
    }
}

extern "C" void kernel_launch(void* const* d_in, const int* in_sizes, int n_in,
                              void* d_out, int out_size, void* d_ws, size_t ws_size,
                              hipStream_t stream) {
    const float* X = (const float*)d_in[0];
    const float* W = (const float*)d_in[1];
    float* out = (float*)d_out;
    float* ws  = (float*)d_ws;

    (void)hipMemsetAsync(d_ws, 0, 256 * sizeof(float), stream);   // loss slots
    vq_init<<<9, 512, 0, stream>>>(W, ws);
    vq_main<<<1024, 256, 0, stream>>>(X, W, out, ws);
    vq_fin<<<1, 512, 0, stream>>>(ws, out);
}